// Round 1
// baseline (425.219 us; speedup 1.0000x reference)
//
#include <hip/hip_runtime.h>

#define B_ 8
#define S_ 2048
#define E_ 1024
#define H_ 1024

typedef __attribute__((ext_vector_type(8))) short bf16x8;
typedef __attribute__((ext_vector_type(4))) float f32x4;

__device__ inline short f2bf(float f) {
  unsigned u = __builtin_bit_cast(unsigned, f);
  unsigned r = u + 0x7FFFu + ((u >> 16) & 1u);   // RNE
  return (short)(r >> 16);
}
__device__ inline float bf2f(short s) {
  unsigned u = ((unsigned)(unsigned short)s) << 16;
  return __builtin_bit_cast(float, u);
}

__device__ inline void async16(const void* g, void* l) {
  __builtin_amdgcn_global_load_lds((const __attribute__((address_space(1))) void*)g,
                                   (__attribute__((address_space(3))) void*)l,
                                   16, 0, 0);
}

// ---------------- X fp32 -> bf16 ----------------
__global__ __launch_bounds__(256)
void cvt_f32_bf16(const float* __restrict__ in, short* __restrict__ out, int n4) {
  int i = blockIdx.x * blockDim.x + threadIdx.x;
  const int stride = gridDim.x * blockDim.x;
  for (; i < n4; i += stride) {
    float4 v = ((const float4*)in)[i];
    short4 o;
    o.x = f2bf(v.x); o.y = f2bf(v.y); o.z = f2bf(v.z); o.w = f2bf(v.w);
    ((short4*)out)[i] = o;
  }
}

// ---------------- W [E][H] fp32 -> Wt [H][E] bf16 (x3) ----------------
__global__ __launch_bounds__(256)
void transpose_w(const float* __restrict__ W0, const float* __restrict__ W1,
                 const float* __restrict__ W2, short* __restrict__ Wt) {
  const float* W = (blockIdx.z == 0) ? W0 : (blockIdx.z == 1) ? W1 : W2;
  short* out = Wt + (size_t)blockIdx.z * H_ * E_;
  __shared__ __align__(16) float t[64][65];
  const int h0 = blockIdx.x * 64, e0 = blockIdx.y * 64;
  const int r = threadIdx.x >> 4;        // 0..15
  const int c = (threadIdx.x & 15) * 4;  // 0..60
#pragma unroll
  for (int p = 0; p < 4; ++p) {
    int rr = r + p * 16;
    float4 v = *(const float4*)&W[(size_t)(e0 + rr) * H_ + h0 + c];
    t[rr][c + 0] = v.x; t[rr][c + 1] = v.y; t[rr][c + 2] = v.z; t[rr][c + 3] = v.w;
  }
  __syncthreads();
#pragma unroll
  for (int p = 0; p < 4; ++p) {
    int rr = r + p * 16;  // h-local
    short4 o;
    o.x = f2bf(t[c + 0][rr]); o.y = f2bf(t[c + 1][rr]);
    o.z = f2bf(t[c + 2][rr]); o.w = f2bf(t[c + 3][rr]);
    *(short4*)&out[(size_t)(h0 + rr) * E_ + e0 + c] = o;
  }
}

// ---------------- V [S][H] bf16 -> Vt [H][S] bf16 (per batch) ----------------
__global__ __launch_bounds__(256)
void transpose_v(const short* __restrict__ V, short* __restrict__ Vt) {
  const int b = blockIdx.z;
  const short* in = V + (size_t)b * S_ * H_;
  short* out = Vt + (size_t)b * H_ * S_;
  __shared__ __align__(16) short t[64][72];
  const int h0 = blockIdx.x * 64, s0 = blockIdx.y * 64;
  const int r = threadIdx.x >> 3;       // 0..31
  const int c = (threadIdx.x & 7) * 8;  // 0..56
#pragma unroll
  for (int p = 0; p < 2; ++p) {
    int rr = r + p * 32;
    *(int4*)&t[rr][c] = *(const int4*)&in[(size_t)(s0 + rr) * H_ + h0 + c];
  }
  __syncthreads();
#pragma unroll
  for (int p = 0; p < 2; ++p) {
    int rr = r + p * 32;  // h-local
    bf16x8 o;
#pragma unroll
    for (int j = 0; j < 8; ++j) o[j] = t[c + j][rr];
    *(bf16x8*)&out[(size_t)(h0 + rr) * S_ + s0 + c] = o;
  }
}

// ---------------- GEMM: C = A @ Bt^T  (A:[M][K], Bt:[N][K], both bf16) -------
// MODE 0: +bias, out bf16            (QKV projection)
// MODE 1: *scale, out bf16, skip tiles above diagonal (scores)
// MODE 2: out fp32, K-loop truncated at diagonal      (PV)
template <int MODE>
__global__ __launch_bounds__(256)
void gemm_k(const short* __restrict__ A, const short* __restrict__ Bt,
            void* __restrict__ Cv, const float* __restrict__ bias,
            int K, int ldA, int ldBt, int ldC,
            size_t zsA, size_t zsB, size_t zsC, float scale) {
  const int bx = blockIdx.x, by = blockIdx.y, z = blockIdx.z;
  if (MODE == 1 && bx > by) return;
  A  += (size_t)z * zsA;
  Bt += (size_t)z * zsB;

  __shared__ __align__(16) short tA[128 * 32];
  __shared__ __align__(16) short tB[128 * 32];

  const int tid = threadIdx.x;
  const int lane = tid & 63;
  const int wv = tid >> 6;           // 0..3
  const int wr = wv >> 1, wc = wv & 1;
  const int lr = lane & 15, kg = lane >> 4;

  const int m0 = by * 128, n0 = bx * 128;
  const int kEnd = (MODE == 2) ? (by + 1) * 128 : K;

  f32x4 acc[4][4];
#pragma unroll
  for (int m = 0; m < 4; ++m)
#pragma unroll
    for (int n = 0; n < 4; ++n) acc[m][n] = (f32x4){0.f, 0.f, 0.f, 0.f};

  for (int k0 = 0; k0 < kEnd; k0 += 32) {
    const int boff0 = wv * 2048;  // this wave's byte chunk of the 8 KB tile
#pragma unroll
    for (int i = 0; i < 2; ++i) {
      int boff = boff0 + i * 1024;
      int eoff = (boff >> 1) + lane * 8;  // bf16 element offset (lane*16B)
      int row = eoff >> 5, col = eoff & 31;
      async16(A  + (size_t)(m0 + row) * ldA  + k0 + col, (char*)tA + boff);
      async16(Bt + (size_t)(n0 + row) * ldBt + k0 + col, (char*)tB + boff);
    }
    asm volatile("s_waitcnt vmcnt(0)" ::: "memory");
    __syncthreads();

    bf16x8 af[4], bfr[4];
#pragma unroll
    for (int m = 0; m < 4; ++m)
      af[m] = *(const bf16x8*)&tA[(wr * 64 + m * 16 + lr) * 32 + kg * 8];
#pragma unroll
    for (int n = 0; n < 4; ++n)
      bfr[n] = *(const bf16x8*)&tB[(wc * 64 + n * 16 + lr) * 32 + kg * 8];
#pragma unroll
    for (int m = 0; m < 4; ++m)
#pragma unroll
      for (int n = 0; n < 4; ++n)
        acc[m][n] = __builtin_amdgcn_mfma_f32_16x16x32_bf16(af[m], bfr[n], acc[m][n], 0, 0, 0);
    __syncthreads();
  }

  // D layout (verified m89): col = lane&15, row = (lane>>4)*4 + reg
#pragma unroll
  for (int m = 0; m < 4; ++m) {
    int rowb = m0 + wr * 64 + m * 16 + kg * 4;
#pragma unroll
    for (int n = 0; n < 4; ++n) {
      int col = n0 + wc * 64 + n * 16 + lr;
      f32x4 v = acc[m][n];
      if (MODE == 0) {
        float bb = bias[col];
        short* C = (short*)Cv;
#pragma unroll
        for (int r = 0; r < 4; ++r)
          C[(size_t)(rowb + r) * ldC + col] = f2bf(v[r] + bb);
      } else if (MODE == 1) {
        short* C = (short*)Cv + (size_t)z * zsC;
#pragma unroll
        for (int r = 0; r < 4; ++r)
          C[(size_t)(rowb + r) * ldC + col] = f2bf(v[r] * scale);
      } else {
        float* C = (float*)Cv + (size_t)z * zsC;
#pragma unroll
        for (int r = 0; r < 4; ++r)
          C[(size_t)(rowb + r) * ldC + col] = v[r];
      }
    }
  }
}

// ---------------- causal row softmax, in place on bf16 scores ----------------
__global__ __launch_bounds__(256)
void softmax_causal(short* __restrict__ P) {
  const int g = blockIdx.x;       // 0 .. B*S-1
  const int q = g & (S_ - 1);     // row within batch
  short* row = P + (size_t)g * S_;
  const int t = threadIdx.x;
  const int lane = t & 63, wv = t >> 6;

  bf16x8 raw = *(const bf16x8*)&row[t * 8];
  float v[8];
  float mx = -3.0e38f;
#pragma unroll
  for (int j = 0; j < 8; ++j) {
    int k = t * 8 + j;
    v[j] = (k <= q) ? bf2f(raw[j]) : -3.0e38f;
    mx = fmaxf(mx, v[j]);
  }
#pragma unroll
  for (int off = 32; off; off >>= 1) mx = fmaxf(mx, __shfl_xor(mx, off));
  __shared__ float redm[4], reds[4];
  if (lane == 0) redm[wv] = mx;
  __syncthreads();
  mx = fmaxf(fmaxf(redm[0], redm[1]), fmaxf(redm[2], redm[3]));

  float sum = 0.f;
#pragma unroll
  for (int j = 0; j < 8; ++j) {
    int k = t * 8 + j;
    float e = (k <= q) ? __expf(v[j] - mx) : 0.f;
    v[j] = e;
    sum += e;
  }
#pragma unroll
  for (int off = 32; off; off >>= 1) sum += __shfl_xor(sum, off);
  if (lane == 0) reds[wv] = sum;
  __syncthreads();
  sum = reds[0] + reds[1] + reds[2] + reds[3];
  float inv = 1.f / sum;

  bf16x8 o;
#pragma unroll
  for (int j = 0; j < 8; ++j) o[j] = f2bf(v[j] * inv);
  *(bf16x8*)&row[t * 8] = o;
}

extern "C" void kernel_launch(void* const* d_in, const int* in_sizes, int n_in,
                              void* d_out, int out_size, void* d_ws, size_t ws_size,
                              hipStream_t stream) {
  const float* X  = (const float*)d_in[0];
  const float* Wq = (const float*)d_in[1];
  const float* bq = (const float*)d_in[2];
  const float* Wk = (const float*)d_in[3];
  const float* bk = (const float*)d_in[4];
  const float* Wv = (const float*)d_in[5];
  const float* bv = (const float*)d_in[6];

  // Workspace layout (166.3 MB total), overlays:
  //   [0,64MB)   scores/P bf16 [B][S][S]  -- early: Xbf [0,32MB), V [32,64MB)
  //   [64,96)    Q bf16, [96,128) K bf16, [128,160) Vt bf16, [160,166.3) Wt bf16 x3
  char* ws = (char*)d_ws;
  const size_t MB = 1024ull * 1024ull;
  short* Pbuf = (short*)ws;
  short* Xbf  = (short*)ws;
  short* V    = (short*)(ws + 32 * MB);
  short* Q    = (short*)(ws + 64 * MB);
  short* Kb   = (short*)(ws + 96 * MB);
  short* Vt   = (short*)(ws + 128 * MB);
  short* Wt   = (short*)(ws + 160 * MB);

  // 1) X -> bf16
  cvt_f32_bf16<<<2048, 256, 0, stream>>>(X, Xbf, (int)((size_t)B_ * S_ * E_ / 4));
  // 2) W -> W^T bf16 (x3)
  transpose_w<<<dim3(H_ / 64, E_ / 64, 3), 256, 0, stream>>>(Wq, Wk, Wv, Wt);
  // 3) Q/K/V projections (+bias), bf16 out
  gemm_k<0><<<dim3(H_ / 128, (B_ * S_) / 128, 1), 256, 0, stream>>>(
      Xbf, Wt,              Q,  bq, E_, E_, E_, H_, 0, 0, 0, 1.f);
  gemm_k<0><<<dim3(H_ / 128, (B_ * S_) / 128, 1), 256, 0, stream>>>(
      Xbf, Wt + H_ * E_,    Kb, bk, E_, E_, E_, H_, 0, 0, 0, 1.f);
  gemm_k<0><<<dim3(H_ / 128, (B_ * S_) / 128, 1), 256, 0, stream>>>(
      Xbf, Wt + 2 * H_ * E_, V, bv, E_, E_, E_, H_, 0, 0, 0, 1.f);
  // 4) V -> V^T
  transpose_v<<<dim3(H_ / 64, S_ / 64, B_), 256, 0, stream>>>(V, Vt);
  // 5) scores = Q K^T / sqrt(H), bf16, lower+diagonal tiles only
  gemm_k<1><<<dim3(S_ / 128, S_ / 128, B_), 256, 0, stream>>>(
      Q, Kb, Pbuf, nullptr, H_, H_, H_, S_,
      (size_t)S_ * H_, (size_t)S_ * H_, (size_t)S_ * S_, 0.03125f);
  // 6) causal softmax, in place (zeros above diagonal)
  softmax_causal<<<B_ * S_, 256, 0, stream>>>(Pbuf);
  // 7) out = P @ V  (fp32), K truncated at diagonal
  gemm_k<2><<<dim3(H_ / 128, S_ / 128, B_), 256, 0, stream>>>(
      Pbuf, Vt, d_out, nullptr, S_, S_, S_, H_,
      (size_t)S_ * S_, (size_t)H_ * S_, (size_t)S_ * H_, 1.f);
}

// Round 2
// 376.974 us; speedup vs baseline: 1.1280x; 1.1280x over previous
//
#include <hip/hip_runtime.h>

#define B_ 8
#define S_ 2048
#define E_ 1024
#define H_ 1024

typedef __attribute__((ext_vector_type(8))) short bf16x8;
typedef __attribute__((ext_vector_type(4))) float f32x4;

__device__ inline short f2bf(float f) {
  unsigned u = __builtin_bit_cast(unsigned, f);
  unsigned r = u + 0x7FFFu + ((u >> 16) & 1u);   // RNE
  return (short)(r >> 16);
}
__device__ inline float bf2f(short s) {
  unsigned u = ((unsigned)(unsigned short)s) << 16;
  return __builtin_bit_cast(float, u);
}

__device__ inline void async16(const void* g, void* l) {
  __builtin_amdgcn_global_load_lds((const __attribute__((address_space(1))) void*)g,
                                   (__attribute__((address_space(3))) void*)l,
                                   16, 0, 0);
}

// ---------------- X fp32 -> bf16 ----------------
__global__ __launch_bounds__(256)
void cvt_f32_bf16(const float* __restrict__ in, short* __restrict__ out, int n4) {
  int i = blockIdx.x * blockDim.x + threadIdx.x;
  const int stride = gridDim.x * blockDim.x;
  for (; i < n4; i += stride) {
    float4 v = ((const float4*)in)[i];
    short4 o;
    o.x = f2bf(v.x); o.y = f2bf(v.y); o.z = f2bf(v.z); o.w = f2bf(v.w);
    ((short4*)out)[i] = o;
  }
}

// ---------------- W [E][H] fp32 -> Wt [H][E] bf16 (x3, concatenated) --------
__global__ __launch_bounds__(256)
void transpose_w(const float* __restrict__ W0, const float* __restrict__ W1,
                 const float* __restrict__ W2, short* __restrict__ Wt) {
  const float* W = (blockIdx.z == 0) ? W0 : (blockIdx.z == 1) ? W1 : W2;
  short* out = Wt + (size_t)blockIdx.z * H_ * E_;
  __shared__ __align__(16) float t[64][65];
  const int h0 = blockIdx.x * 64, e0 = blockIdx.y * 64;
  const int r = threadIdx.x >> 4;        // 0..15
  const int c = (threadIdx.x & 15) * 4;  // 0..60
#pragma unroll
  for (int p = 0; p < 4; ++p) {
    int rr = r + p * 16;
    float4 v = *(const float4*)&W[(size_t)(e0 + rr) * H_ + h0 + c];
    t[rr][c + 0] = v.x; t[rr][c + 1] = v.y; t[rr][c + 2] = v.z; t[rr][c + 3] = v.w;
  }
  __syncthreads();
#pragma unroll
  for (int p = 0; p < 4; ++p) {
    int rr = r + p * 16;  // h-local
    short4 o;
    o.x = f2bf(t[c + 0][rr]); o.y = f2bf(t[c + 1][rr]);
    o.z = f2bf(t[c + 2][rr]); o.w = f2bf(t[c + 3][rr]);
    *(short4*)&out[(size_t)(h0 + rr) * E_ + e0 + c] = o;
  }
}

// ---------------- V [S][H] bf16 -> Vt [H][S] bf16 (per batch) ----------------
__global__ __launch_bounds__(256)
void transpose_v(const short* __restrict__ V, short* __restrict__ Vt) {
  const int b = blockIdx.z;
  const short* in = V + (size_t)b * S_ * H_;
  short* out = Vt + (size_t)b * H_ * S_;
  __shared__ __align__(16) short t[64][72];
  const int h0 = blockIdx.x * 64, s0 = blockIdx.y * 64;
  const int r = threadIdx.x >> 3;       // 0..31
  const int c = (threadIdx.x & 7) * 8;  // 0..56
#pragma unroll
  for (int p = 0; p < 2; ++p) {
    int rr = r + p * 32;
    *(int4*)&t[rr][c] = *(const int4*)&in[(size_t)(s0 + rr) * H_ + h0 + c];
  }
  __syncthreads();
#pragma unroll
  for (int p = 0; p < 2; ++p) {
    int rr = r + p * 32;  // h-local
    bf16x8 o;
#pragma unroll
    for (int j = 0; j < 8; ++j) o[j] = t[c + j][rr];
    *(bf16x8*)&out[(size_t)(h0 + rr) * S_ + s0 + c] = o;
  }
}

// ------------- GEMM 256x256 / BK=64 / 8 waves / 2-phase double-buffer -------
// C = A @ Bt^T   (A:[M][K] bf16, Bt:[N][K] bf16)
// MODE 0: +bias, out bf16, N=3072 split into Q/K/V segments (proj)
// MODE 1: *scale, out bf16, skip tiles above diagonal       (scores)
// MODE 2: out fp32, K-loop truncated at diagonal            (PV)
template <int MODE>
__global__ __launch_bounds__(512, 2)
void gemm2(const short* __restrict__ A, const short* __restrict__ Bt,
           void* __restrict__ C0, void* __restrict__ C1, void* __restrict__ C2,
           const float* __restrict__ b0, const float* __restrict__ b1,
           const float* __restrict__ b2,
           int K, int ldA, int ldBt, int ldC,
           size_t zsA, size_t zsB, size_t zsC, float scale) {
  const int bx = blockIdx.x, by = blockIdx.y, z = blockIdx.z;
  if (MODE == 1 && bx > by) return;
  A  += (size_t)z * zsA;
  Bt += (size_t)z * zsB;

  __shared__ __align__(16) short tA[2][256 * 64];
  __shared__ __align__(16) short tB[2][256 * 64];

  const int tid = threadIdx.x;
  const int lane = tid & 63;
  const int wv = tid >> 6;            // 0..7
  const int wr = wv >> 2, wc = wv & 3;
  const int lr = lane & 15, kg = lane >> 4;
  const int m0 = by * 256, n0 = bx * 256;
  const int kEnd = (MODE == 2) ? (by + 1) * 256 : K;
  const int nt = kEnd >> 6;           // >= 4 always here

  f32x4 acc[8][4];
#pragma unroll
  for (int m = 0; m < 8; ++m)
#pragma unroll
    for (int n = 0; n < 4; ++n) acc[m][n] = (f32x4){0.f, 0.f, 0.f, 0.f};

  // stage one full K-tile (A 32KB + B 32KB) into buffer `buf`
  auto STAGE = [&](int buf, int k0) {
#pragma unroll
    for (int r = 0; r < 4; ++r) {
      int boff = r * 8192 + tid * 16;       // byte slot in [256][64] bf16 tile
      int row = boff >> 7;                   // /128B per row
      int cs  = (boff & 127) >> 1;           // short col
      async16(A  + (size_t)(m0 + row) * ldA  + k0 + cs,
              (char*)&tA[buf][0] + r * 8192 + wv * 1024);
      async16(Bt + (size_t)(n0 + row) * ldBt + k0 + cs,
              (char*)&tB[buf][0] + r * 8192 + wv * 1024);
    }
  };

  auto COMPUTE = [&](int buf) {
#pragma unroll
    for (int ks = 0; ks < 2; ++ks) {
      bf16x8 bfr[4];
#pragma unroll
      for (int n = 0; n < 4; ++n)
        bfr[n] = *(const bf16x8*)&tB[buf][(wc * 64 + n * 16 + lr) * 64 + ks * 32 + kg * 8];
#pragma unroll
      for (int mh = 0; mh < 2; ++mh) {
        bf16x8 af[4];
#pragma unroll
        for (int mm = 0; mm < 4; ++mm)
          af[mm] = *(const bf16x8*)&tA[buf][(wr * 128 + mh * 64 + mm * 16 + lr) * 64 + ks * 32 + kg * 8];
#pragma unroll
        for (int mm = 0; mm < 4; ++mm)
#pragma unroll
          for (int n = 0; n < 4; ++n)
            acc[mh * 4 + mm][n] = __builtin_amdgcn_mfma_f32_16x16x32_bf16(
                af[mm], bfr[n], acc[mh * 4 + mm][n], 0, 0, 0);
      }
    }
  };

  STAGE(0, 0);
  asm volatile("s_waitcnt vmcnt(0)" ::: "memory");
  __syncthreads();
  int cur = 0;
  for (int t = 0; t < nt - 1; ++t) {
    STAGE(cur ^ 1, (t + 1) << 6);   // issue next-tile loads first
    COMPUTE(cur);                   // MFMA hides the in-flight loads
    asm volatile("s_waitcnt vmcnt(0)" ::: "memory");
    __syncthreads();
    cur ^= 1;
  }
  COMPUTE(cur);

  // D layout: col = lane&15, row = (lane>>4)*4 + reg
#pragma unroll
  for (int m = 0; m < 8; ++m) {
    int rowb = m0 + wr * 128 + m * 16 + kg * 4;
#pragma unroll
    for (int n = 0; n < 4; ++n) {
      int col = n0 + wc * 64 + n * 16 + lr;
      f32x4 v = acc[m][n];
      if (MODE == 0) {
        int seg = n0 >> 10;  // block-uniform: 0=Q 1=K 2=V
        const float* bp = (seg == 0) ? b0 : (seg == 1) ? b1 : b2;
        short* C = (short*)((seg == 0) ? C0 : (seg == 1) ? C1 : C2);
        int cl = col & 1023;
        float bb = bp[cl];
#pragma unroll
        for (int r = 0; r < 4; ++r)
          C[(size_t)(rowb + r) * ldC + cl] = f2bf(v[r] + bb);
      } else if (MODE == 1) {
        short* C = (short*)C0 + (size_t)z * zsC;
#pragma unroll
        for (int r = 0; r < 4; ++r)
          C[(size_t)(rowb + r) * ldC + col] = f2bf(v[r] * scale);
      } else {
        float* C = (float*)C0 + (size_t)z * zsC;
#pragma unroll
        for (int r = 0; r < 4; ++r)
          C[(size_t)(rowb + r) * ldC + col] = v[r];
      }
    }
  }
}

// ---------------- causal row softmax, in place on bf16 scores ----------------
__global__ __launch_bounds__(256)
void softmax_causal(short* __restrict__ P) {
  const int g = blockIdx.x;       // 0 .. B*S-1
  const int q = g & (S_ - 1);     // row within batch
  short* row = P + (size_t)g * S_;
  const int t = threadIdx.x;
  const int lane = t & 63, wv = t >> 6;

  bf16x8 raw = *(const bf16x8*)&row[t * 8];
  float v[8];
  float mx = -3.0e38f;
#pragma unroll
  for (int j = 0; j < 8; ++j) {
    int k = t * 8 + j;
    v[j] = (k <= q) ? bf2f(raw[j]) : -3.0e38f;
    mx = fmaxf(mx, v[j]);
  }
#pragma unroll
  for (int off = 32; off; off >>= 1) mx = fmaxf(mx, __shfl_xor(mx, off));
  __shared__ float redm[4], reds[4];
  if (lane == 0) redm[wv] = mx;
  __syncthreads();
  mx = fmaxf(fmaxf(redm[0], redm[1]), fmaxf(redm[2], redm[3]));

  float sum = 0.f;
#pragma unroll
  for (int j = 0; j < 8; ++j) {
    int k = t * 8 + j;
    float e = (k <= q) ? __expf(v[j] - mx) : 0.f;
    v[j] = e;
    sum += e;
  }
#pragma unroll
  for (int off = 32; off; off >>= 1) sum += __shfl_xor(sum, off);
  if (lane == 0) reds[wv] = sum;
  __syncthreads();
  sum = reds[0] + reds[1] + reds[2] + reds[3];
  float inv = 1.f / sum;

  bf16x8 o;
#pragma unroll
  for (int j = 0; j < 8; ++j) o[j] = f2bf(v[j] * inv);
  *(bf16x8*)&row[t * 8] = o;
}

extern "C" void kernel_launch(void* const* d_in, const int* in_sizes, int n_in,
                              void* d_out, int out_size, void* d_ws, size_t ws_size,
                              hipStream_t stream) {
  const float* X  = (const float*)d_in[0];
  const float* Wq = (const float*)d_in[1];
  const float* bq = (const float*)d_in[2];
  const float* Wk = (const float*)d_in[3];
  const float* bk = (const float*)d_in[4];
  const float* Wv = (const float*)d_in[5];
  const float* bv = (const float*)d_in[6];

  // Workspace layout (166.3 MB), overlays:
  //   [0,64MB)   scores/P bf16 [B][S][S]  -- early: Xbf [0,32MB)
  //   [64,96)    Q bf16, [96,128) K bf16, [32,64)+proj-phase V bf16,
  //   [128,160)  Vt bf16, [160,166.3) Wt bf16 x3 (concatenated [3072][1024])
  char* ws = (char*)d_ws;
  const size_t MB = 1024ull * 1024ull;
  short* Pbuf = (short*)ws;
  short* Xbf  = (short*)ws;
  short* V    = (short*)(ws + 32 * MB);
  short* Q    = (short*)(ws + 64 * MB);
  short* Kb   = (short*)(ws + 96 * MB);
  short* Vt   = (short*)(ws + 128 * MB);
  short* Wt   = (short*)(ws + 160 * MB);

  // 1) X -> bf16
  cvt_f32_bf16<<<2048, 256, 0, stream>>>(X, Xbf, (int)((size_t)B_ * S_ * E_ / 4));
  // 2) W -> W^T bf16 (x3 concatenated -> [3072][1024])
  transpose_w<<<dim3(H_ / 64, E_ / 64, 3), 256, 0, stream>>>(Wq, Wk, Wv, Wt);
  // 3) fused QKV projection: [16384,1024] x [3072,1024]^T
  gemm2<0><<<dim3(3 * H_ / 256, (B_ * S_) / 256, 1), 512, 0, stream>>>(
      Xbf, Wt, Q, Kb, V, bq, bk, bv, E_, E_, E_, H_, 0, 0, 0, 1.f);
  // 4) V -> V^T
  transpose_v<<<dim3(H_ / 64, S_ / 64, B_), 256, 0, stream>>>(V, Vt);
  // 5) scores = Q K^T / sqrt(H), bf16, lower+diagonal 256-tiles only
  gemm2<1><<<dim3(S_ / 256, S_ / 256, B_), 512, 0, stream>>>(
      Q, Kb, Pbuf, nullptr, nullptr, nullptr, nullptr, nullptr,
      H_, H_, H_, S_, (size_t)S_ * H_, (size_t)S_ * H_, (size_t)S_ * S_, 0.03125f);
  // 6) causal softmax, in place (writes zeros above diagonal)
  softmax_causal<<<B_ * S_, 256, 0, stream>>>(Pbuf);
  // 7) out = P @ V (fp32), K truncated at diagonal 256-tile
  gemm2<2><<<dim3(H_ / 256, S_ / 256, B_), 512, 0, stream>>>(
      Pbuf, Vt, d_out, nullptr, nullptr, nullptr, nullptr, nullptr,
      S_, S_, S_, H_, (size_t)S_ * S_, (size_t)H_ * S_, (size_t)S_ * H_, 1.f);
}

// Round 3
// 315.841 us; speedup vs baseline: 1.3463x; 1.1936x over previous
//
#include <hip/hip_runtime.h>

#define B_ 8
#define S_ 2048
#define E_ 1024
#define H_ 1024

typedef __attribute__((ext_vector_type(8))) short bf16x8;
typedef __attribute__((ext_vector_type(4))) float f32x4;

__device__ inline short f2bf(float f) {
  unsigned u = __builtin_bit_cast(unsigned, f);
  unsigned r = u + 0x7FFFu + ((u >> 16) & 1u);   // RNE
  return (short)(r >> 16);
}
__device__ inline float bf2f(short s) {
  unsigned u = ((unsigned)(unsigned short)s) << 16;
  return __builtin_bit_cast(float, u);
}

__device__ inline void async16(const void* g, void* l) {
  __builtin_amdgcn_global_load_lds((const __attribute__((address_space(1))) void*)g,
                                   (__attribute__((address_space(3))) void*)l,
                                   16, 0, 0);
}

// ---------------- X fp32 -> bf16 ----------------
__global__ __launch_bounds__(256)
void cvt_f32_bf16(const float* __restrict__ in, short* __restrict__ out, int n4) {
  int i = blockIdx.x * blockDim.x + threadIdx.x;
  const int stride = gridDim.x * blockDim.x;
  for (; i < n4; i += stride) {
    float4 v = ((const float4*)in)[i];
    short4 o;
    o.x = f2bf(v.x); o.y = f2bf(v.y); o.z = f2bf(v.z); o.w = f2bf(v.w);
    ((short4*)out)[i] = o;
  }
}

// ---------------- W [E][H] fp32 -> Wt [H][E] bf16 (x3, concatenated) --------
__global__ __launch_bounds__(256)
void transpose_w(const float* __restrict__ W0, const float* __restrict__ W1,
                 const float* __restrict__ W2, short* __restrict__ Wt) {
  const float* W = (blockIdx.z == 0) ? W0 : (blockIdx.z == 1) ? W1 : W2;
  short* out = Wt + (size_t)blockIdx.z * H_ * E_;
  __shared__ __align__(16) float t[64][65];
  const int h0 = blockIdx.x * 64, e0 = blockIdx.y * 64;
  const int r = threadIdx.x >> 4;        // 0..15
  const int c = (threadIdx.x & 15) * 4;  // 0..60
#pragma unroll
  for (int p = 0; p < 4; ++p) {
    int rr = r + p * 16;
    float4 v = *(const float4*)&W[(size_t)(e0 + rr) * H_ + h0 + c];
    t[rr][c + 0] = v.x; t[rr][c + 1] = v.y; t[rr][c + 2] = v.z; t[rr][c + 3] = v.w;
  }
  __syncthreads();
#pragma unroll
  for (int p = 0; p < 4; ++p) {
    int rr = r + p * 16;  // h-local
    short4 o;
    o.x = f2bf(t[c + 0][rr]); o.y = f2bf(t[c + 1][rr]);
    o.z = f2bf(t[c + 2][rr]); o.w = f2bf(t[c + 3][rr]);
    *(short4*)&out[(size_t)(h0 + rr) * E_ + e0 + c] = o;
  }
}

// ---------------- V [S][H] bf16 -> Vt [H][S] bf16 (per batch) ----------------
__global__ __launch_bounds__(256)
void transpose_v(const short* __restrict__ V, short* __restrict__ Vt) {
  const int b = blockIdx.z;
  const short* in = V + (size_t)b * S_ * H_;
  short* out = Vt + (size_t)b * H_ * S_;
  __shared__ __align__(16) short t[64][72];
  const int h0 = blockIdx.x * 64, s0 = blockIdx.y * 64;
  const int r = threadIdx.x >> 3;       // 0..31
  const int c = (threadIdx.x & 7) * 8;  // 0..56
#pragma unroll
  for (int p = 0; p < 2; ++p) {
    int rr = r + p * 32;
    *(int4*)&t[rr][c] = *(const int4*)&in[(size_t)(s0 + rr) * H_ + h0 + c];
  }
  __syncthreads();
#pragma unroll
  for (int p = 0; p < 2; ++p) {
    int rr = r + p * 32;  // h-local
    bf16x8 o;
#pragma unroll
    for (int j = 0; j < 8; ++j) o[j] = t[c + j][rr];
    *(bf16x8*)&out[(size_t)(h0 + rr) * S_ + s0 + c] = o;
  }
}

// ======================= 8-phase 256x256 GEMM (T2+T3+T4+T5) ==================
// C = A @ Bt^T, A:[M][K] bf16, Bt:[N][K] bf16, BK=64, 8 waves (2Mx4N),
// LDS [buf][ks] half-tiles [256][32] bf16 (16KB), st-swizzle byte^=((b>>9)&1)<<5.
// MODE 0: +bias, out bf16 segmented Q/K/V; MODE 1: *scale bf16, causal tile
// skip; MODE 2: fp32 out, K truncated at diagonal.

#define BAR() asm volatile("s_barrier" ::: "memory")
#define VMC(n) asm volatile("s_waitcnt vmcnt(" #n ")" ::: "memory")

#define RD_B(buf, ks)                                                        \
  _Pragma("unroll")                                                          \
  for (int n = 0; n < 4; ++n)                                                \
    bfr[n] = *(const bf16x8*)(lBp + (buf) * 32768 + (ks) * 16384 +           \
                              ((wc * 64 + n * 16 + lr) << 6) + aCol)

#define RD_A(buf, ks, mh)                                                    \
  _Pragma("unroll")                                                          \
  for (int m = 0; m < 4; ++m)                                                \
    af[m] = *(const bf16x8*)(lAp + (buf) * 32768 + (ks) * 16384 +            \
                             ((wr * 128 + (mh) * 64 + m * 16 + lr) << 6) + aCol)

#define MFMA16(mh)                                                           \
  _Pragma("unroll")                                                          \
  for (int m = 0; m < 4; ++m) {                                              \
    _Pragma("unroll")                                                        \
    for (int n = 0; n < 4; ++n)                                              \
      acc[(mh) * 4 + m][n] = __builtin_amdgcn_mfma_f32_16x16x32_bf16(        \
          af[m], bfr[n], acc[(mh) * 4 + m][n], 0, 0, 0);                     \
  }

#define STAGE_A(buf, ks, kt) do {                                            \
    const short* _s = A + (size_t)(m0 + srow) * ldA + (kt) * 64 + (ks) * 32 + scol; \
    char* _d = (char*)lAp + (buf) * 32768 + (ks) * 16384 + wv * 1024;        \
    async16(_s, _d);                                                         \
    async16(_s + (size_t)128 * ldA, _d + 8192);                              \
  } while (0)

#define STAGE_B(buf, ks, kt) do {                                            \
    const short* _s = Bt + (size_t)(n0 + srow) * ldBt + (kt) * 64 + (ks) * 32 + scol; \
    char* _d = (char*)lBp + (buf) * 32768 + (ks) * 16384 + wv * 1024;        \
    async16(_s, _d);                                                         \
    async16(_s + (size_t)128 * ldBt, _d + 8192);                             \
  } while (0)

#define PHASE(buf, ks, mh, STG, WT) do {                                     \
    if ((mh) == 0) { RD_B(buf, ks); }                                        \
    RD_A(buf, ks, mh);                                                       \
    STG;                                                                     \
    WT;                                                                      \
    BAR();                                                                   \
    asm volatile("s_waitcnt lgkmcnt(0)" ::: "memory");                       \
    __builtin_amdgcn_sched_barrier(0);                                       \
    __builtin_amdgcn_s_setprio(1);                                           \
    MFMA16(mh);                                                              \
    __builtin_amdgcn_s_setprio(0);                                           \
    BAR();                                                                   \
  } while (0)

template <int MODE>
__global__ __launch_bounds__(512, 2)
void gemm8(const short* __restrict__ A, const short* __restrict__ Bt,
           void* __restrict__ C0, void* __restrict__ C1, void* __restrict__ C2,
           const float* __restrict__ b0, const float* __restrict__ b1,
           const float* __restrict__ b2,
           int K, int ldA, int ldBt, int ldC,
           size_t zsA, size_t zsB, size_t zsC, float scale) {
  const int bx = blockIdx.x, by = blockIdx.y, z = blockIdx.z;
  if (MODE == 1 && bx > by) return;
  A  += (size_t)z * zsA;
  Bt += (size_t)z * zsB;

  __shared__ __align__(16) short lA[2][2][256 * 32];  // 64 KB
  __shared__ __align__(16) short lB[2][2][256 * 32];  // 64 KB
  const char* lAp = (const char*)&lA[0][0][0];
  const char* lBp = (const char*)&lB[0][0][0];

  const int tid = threadIdx.x;
  const int lane = tid & 63;
  const int wv = tid >> 6;            // 0..7
  const int wr = wv >> 2, wc = wv & 3;
  const int lr = lane & 15, kg = lane >> 4;
  const int m0 = by * 256, n0 = bx * 256;
  const int kEnd = (MODE == 2) ? (by + 1) * 256 : K;
  const int nt = kEnd >> 6;           // even, >= 4 for all calls here
  const int nIter = nt >> 1;

  // swizzled read column (bytes) within a [256][32] half-tile row
  const int aCol = (kg * 16) ^ ((lr & 8) << 2);
  // staging: linear LDS dest, inverse-swizzled global source
  const int srow = tid >> 2;                                  // +128 for r=1
  const int scol = (((tid & 3) * 16) ^ (tid & 32)) >> 1;      // element col

  f32x4 acc[8][4];
#pragma unroll
  for (int m = 0; m < 8; ++m)
#pragma unroll
    for (int n = 0; n < 4; ++n) acc[m][n] = (f32x4){0.f, 0.f, 0.f, 0.f};
  bf16x8 bfr[4], af[4];

  // Prologue: tile0 all 4 halves, tile1 first 3 halves; vmcnt(6) -> tile0 landed
  STAGE_B(0, 0, 0); STAGE_A(0, 0, 0); STAGE_B(0, 1, 0); STAGE_A(0, 1, 0);
  STAGE_B(1, 0, 1); STAGE_A(1, 0, 1); STAGE_B(1, 1, 1);
  VMC(6);
  BAR();

  for (int i = 0; i < nIter; ++i) {
    const int T = 2 * i;
    const bool lastI = (i == nIter - 1);
    // phases 1-4: compute tile T (buf0); stage T+1's last half then T+2
    PHASE(0, 0, 0, STAGE_A(1, 1, T + 1), (void)0);
    PHASE(0, 0, 1, if (!lastI) { STAGE_B(0, 0, T + 2); }, (void)0);
    PHASE(0, 1, 0, if (!lastI) { STAGE_A(0, 0, T + 2); }, (void)0);
    PHASE(0, 1, 1, if (!lastI) { STAGE_B(0, 1, T + 2); },
          if (lastI) { VMC(0); } else { VMC(6); });
    // phases 5-8: compute tile T+1 (buf1); stage rest of T+2 then T+3
    PHASE(1, 0, 0, if (!lastI) { STAGE_A(0, 1, T + 2); }, (void)0);
    PHASE(1, 0, 1, if (!lastI) { STAGE_B(1, 0, T + 3); }, (void)0);
    PHASE(1, 1, 0, if (!lastI) { STAGE_A(1, 0, T + 3); }, (void)0);
    PHASE(1, 1, 1, if (!lastI) { STAGE_B(1, 1, T + 3); },
          if (!lastI) { VMC(6); });
  }

  // Epilogue. D layout: col = lane&15, row = (lane>>4)*4 + reg
#pragma unroll
  for (int mq = 0; mq < 8; ++mq) {
    int rowb = m0 + wr * 128 + (mq >> 2) * 64 + (mq & 3) * 16 + kg * 4;
#pragma unroll
    for (int n = 0; n < 4; ++n) {
      int col = n0 + wc * 64 + n * 16 + lr;
      f32x4 v = acc[mq][n];
      if (MODE == 0) {
        int seg = n0 >> 10;  // block-uniform: 0=Q 1=K 2=V
        const float* bp = (seg == 0) ? b0 : (seg == 1) ? b1 : b2;
        short* C = (short*)((seg == 0) ? C0 : (seg == 1) ? C1 : C2);
        int cl = col & 1023;
        float bb = bp[cl];
#pragma unroll
        for (int r = 0; r < 4; ++r)
          C[(size_t)(rowb + r) * ldC + cl] = f2bf(v[r] + bb);
      } else if (MODE == 1) {
        short* C = (short*)C0 + (size_t)z * zsC;
#pragma unroll
        for (int r = 0; r < 4; ++r)
          C[(size_t)(rowb + r) * ldC + col] = f2bf(v[r] * scale);
      } else {
        float* C = (float*)C0 + (size_t)z * zsC;
#pragma unroll
        for (int r = 0; r < 4; ++r)
          C[(size_t)(rowb + r) * ldC + col] = v[r];
      }
    }
  }
}

// ---------------- causal row softmax, in place on bf16 scores ----------------
__global__ __launch_bounds__(256)
void softmax_causal(short* __restrict__ P) {
  const int g = blockIdx.x;       // 0 .. B*S-1
  const int q = g & (S_ - 1);     // row within batch
  short* row = P + (size_t)g * S_;
  const int t = threadIdx.x;
  const int lane = t & 63, wv = t >> 6;

  bf16x8 raw = *(const bf16x8*)&row[t * 8];
  float v[8];
  float mx = -3.0e38f;
#pragma unroll
  for (int j = 0; j < 8; ++j) {
    int k = t * 8 + j;
    v[j] = (k <= q) ? bf2f(raw[j]) : -3.0e38f;
    mx = fmaxf(mx, v[j]);
  }
#pragma unroll
  for (int off = 32; off; off >>= 1) mx = fmaxf(mx, __shfl_xor(mx, off));
  __shared__ float redm[4], reds[4];
  if (lane == 0) redm[wv] = mx;
  __syncthreads();
  mx = fmaxf(fmaxf(redm[0], redm[1]), fmaxf(redm[2], redm[3]));

  float sum = 0.f;
#pragma unroll
  for (int j = 0; j < 8; ++j) {
    int k = t * 8 + j;
    float e = (k <= q) ? __expf(v[j] - mx) : 0.f;
    v[j] = e;
    sum += e;
  }
#pragma unroll
  for (int off = 32; off; off >>= 1) sum += __shfl_xor(sum, off);
  if (lane == 0) reds[wv] = sum;
  __syncthreads();
  sum = reds[0] + reds[1] + reds[2] + reds[3];
  float inv = 1.f / sum;

  bf16x8 o;
#pragma unroll
  for (int j = 0; j < 8; ++j) o[j] = f2bf(v[j] * inv);
  *(bf16x8*)&row[t * 8] = o;
}

extern "C" void kernel_launch(void* const* d_in, const int* in_sizes, int n_in,
                              void* d_out, int out_size, void* d_ws, size_t ws_size,
                              hipStream_t stream) {
  const float* X  = (const float*)d_in[0];
  const float* Wq = (const float*)d_in[1];
  const float* bq = (const float*)d_in[2];
  const float* Wk = (const float*)d_in[3];
  const float* bk = (const float*)d_in[4];
  const float* Wv = (const float*)d_in[5];
  const float* bv = (const float*)d_in[6];

  // Workspace layout (166.3 MB), overlays:
  //   [0,64MB)   scores/P bf16 [B][S][S]  -- early: Xbf [0,32MB)
  //   [64,96)    Q bf16, [96,128) K bf16, [32,64) proj-phase V bf16,
  //   [128,160)  Vt bf16, [160,166.3) Wt bf16 x3 (concatenated [3072][1024])
  char* ws = (char*)d_ws;
  const size_t MB = 1024ull * 1024ull;
  short* Pbuf = (short*)ws;
  short* Xbf  = (short*)ws;
  short* V    = (short*)(ws + 32 * MB);
  short* Q    = (short*)(ws + 64 * MB);
  short* Kb   = (short*)(ws + 96 * MB);
  short* Vt   = (short*)(ws + 128 * MB);
  short* Wt   = (short*)(ws + 160 * MB);

  // 1) X -> bf16
  cvt_f32_bf16<<<2048, 256, 0, stream>>>(X, Xbf, (int)((size_t)B_ * S_ * E_ / 4));
  // 2) W -> W^T bf16 (x3 concatenated -> [3072][1024])
  transpose_w<<<dim3(H_ / 64, E_ / 64, 3), 256, 0, stream>>>(Wq, Wk, Wv, Wt);
  // 3) fused QKV projection: [16384,1024] x [3072,1024]^T
  gemm8<0><<<dim3(3 * H_ / 256, (B_ * S_) / 256, 1), 512, 0, stream>>>(
      Xbf, Wt, Q, Kb, V, bq, bk, bv, E_, E_, E_, H_, 0, 0, 0, 1.f);
  // 4) V -> V^T
  transpose_v<<<dim3(H_ / 64, S_ / 64, B_), 256, 0, stream>>>(V, Vt);
  // 5) scores = Q K^T / sqrt(H), bf16, lower+diagonal 256-tiles only
  gemm8<1><<<dim3(S_ / 256, S_ / 256, B_), 512, 0, stream>>>(
      Q, Kb, Pbuf, nullptr, nullptr, nullptr, nullptr, nullptr,
      H_, H_, H_, S_, (size_t)S_ * H_, (size_t)S_ * H_, (size_t)S_ * S_, 0.03125f);
  // 6) causal softmax, in place (writes zeros above diagonal)
  softmax_causal<<<B_ * S_, 256, 0, stream>>>(Pbuf);
  // 7) out = P @ V (fp32), K truncated at diagonal 256-tile
  gemm8<2><<<dim3(H_ / 256, S_ / 256, B_), 512, 0, stream>>>(
      Pbuf, Vt, d_out, nullptr, nullptr, nullptr, nullptr, nullptr,
      S_, S_, S_, H_, (size_t)S_ * S_, (size_t)H_ * S_, (size_t)S_ * H_, 1.f);
}